// Round 4
// baseline (1377.502 us; speedup 1.0000x reference)
//
#include <hip/hip_runtime.h>
#include <cstdint>
#include <cstddef>

#define B_    4
#define L_    1024
#define DIM_  256
#define DI_   512
#define NTOK  (B_*L_)

__device__ __forceinline__ float siluf_(float x){ return x / (1.0f + __expf(-x)); }
__device__ __forceinline__ float softplusf_(float x){
  return (x > 15.0f) ? x : log1pf(__expf(x));
}

// ---------- LayerNorm, materialized: one wave per token ----------
__global__ __launch_bounds__(256) void k_ln(const float* __restrict__ x,
    const float* __restrict__ gamma, const float* __restrict__ beta,
    float* __restrict__ xn){
  int tok  = blockIdx.x * 4 + (threadIdx.x >> 6);
  int lane = threadIdx.x & 63;
  float v[4];
  float s = 0.f, sq = 0.f;
  #pragma unroll
  for (int q = 0; q < 4; q++){
    v[q] = x[(size_t)tok * DIM_ + lane * 4 + q];
    s += v[q]; sq += v[q] * v[q];
  }
  #pragma unroll
  for (int off = 32; off; off >>= 1){
    s  += __shfl_xor(s,  off, 64);
    sq += __shfl_xor(sq, off, 64);
  }
  float mu = s * (1.0f / DIM_);
  float rs = rsqrtf(sq * (1.0f / DIM_) - mu * mu + 1e-5f);
  #pragma unroll
  for (int q = 0; q < 4; q++){
    int c = lane * 4 + q;
    xn[(size_t)tok * DIM_ + c] = (v[q] - mu) * rs * gamma[c] + beta[c];
  }
}

// ---------- GEMM1: xz[m,n] = xn[m,:] . W_in[n,:]  (M=4096,N=1024,K=256) ----------
__global__ __launch_bounds__(256) void k_gemm1s(const float* __restrict__ xn,
    const float* __restrict__ Win, float* __restrict__ xz){
  __shared__ float sh[256];
  int m = blockIdx.y;
  int n = blockIdx.x * 256 + threadIdx.x;
  sh[threadIdx.x] = xn[(size_t)m * 256 + threadIdx.x];
  __syncthreads();
  float acc = 0.f;
  for (int k = 0; k < 256; k++)
    acc += sh[k] * Win[(size_t)n * 256 + k];
  xz[(size_t)m * 1024 + n] = acc;
}

// ---------- causal depthwise conv (w=4) + SiLU ----------
__global__ __launch_bounds__(256) void k_conv(const float* __restrict__ xz,
    const float* __restrict__ cw, const float* __restrict__ cb,
    float* __restrict__ uc){
  int g = blockIdx.x * 256 + threadIdx.x;      // 0 .. NTOK*512-1
  int d = g & 511;
  int tok = g >> 9;
  int t = tok & (L_ - 1);
  float w0 = cw[d*4+0], w1 = cw[d*4+1], w2 = cw[d*4+2], w3 = cw[d*4+3];
  const float* up = xz + (size_t)tok * 1024 + d;  // u = xz[:, :512]
  float acc = cb[d] + w3 * up[0];
  if (t >= 1) acc += w2 * up[-1 * 1024];
  if (t >= 2) acc += w1 * up[-2 * 1024];
  if (t >= 3) acc += w0 * up[-3 * 1024];
  uc[g] = siluf_(acc);
}

// ---------- GEMM2: dbl[m,n] = uc[m,:] . W_x[n,:]  (M=4096,N=80,K=512) ----------
__global__ __launch_bounds__(128) void k_gemm2s(const float* __restrict__ uc,
    const float* __restrict__ Wx, float* __restrict__ dbl){
  __shared__ float sh[512];
  int m = blockIdx.x;
  for (int i = threadIdx.x; i < 512; i += 128)
    sh[i] = uc[(size_t)m * 512 + i];
  __syncthreads();
  int n = threadIdx.x;
  if (n < 80){
    float acc = 0.f;
    for (int k = 0; k < 512; k++)
      acc += sh[k] * Wx[(size_t)n * 512 + k];
    dbl[(size_t)m * 80 + n] = acc;
  }
}

// ---------- dt[m,d] = softplus(dbl[m,:16] . W_dt[d,:] + b_dt[d]) ----------
__global__ __launch_bounds__(256) void k_dt(const float* __restrict__ dbl,
    const float* __restrict__ Wdt, const float* __restrict__ bdt,
    float* __restrict__ dt){
  int g = blockIdx.x * 256 + threadIdx.x;
  int d = g & 511; int m = g >> 9;
  float acc = bdt[d];
  const float* r = dbl + (size_t)m * 80;
  #pragma unroll
  for (int k = 0; k < 16; k++)
    acc += r[k] * Wdt[d * 16 + k];
  dt[g] = softplusf_(acc);
}

// ---------- selective scan: one wave per (b,d); lane = state index ----------
__global__ __launch_bounds__(256) void k_scan(const float* __restrict__ dt,
    const float* __restrict__ uc, const float* __restrict__ dbl,
    const float* __restrict__ C_SA, const float* __restrict__ A_log,
    float* __restrict__ ys){
  int wid  = (blockIdx.x * 256 + threadIdx.x) >> 6;  // 0..2047
  int lane = threadIdx.x & 63;
  int b = wid >> 9;
  int d = wid & 511;
  float A = -__expf(A_log[(size_t)d * 64 + lane]);
  float h = 0.0f;
  int tok0 = b * L_;
  for (int t = 0; t < L_; t++){
    int tok = tok0 + t;
    float dtv = dt[(size_t)tok * 512 + d];
    float uv  = uc[(size_t)tok * 512 + d];
    float Bv  = dbl[(size_t)tok * 80 + 16 + lane];
    float Cv  = C_SA[(size_t)tok * 64 + lane];
    float dA = __expf(dtv * A);
    h = dA * h + (dtv * uv) * Bv;
    float y = h * Cv;
    #pragma unroll
    for (int off = 32; off; off >>= 1) y += __shfl_xor(y, off, 64);
    if (lane == 0) ys[(size_t)tok * 512 + d] = y;
  }
}

// ---------- gate: g[m,k] = (ys + uc*D[k]) * silu(z[m,k]) ----------
__global__ __launch_bounds__(256) void k_gate(const float* __restrict__ ys,
    const float* __restrict__ uc, const float* __restrict__ xz,
    const float* __restrict__ Dp, float* __restrict__ gate){
  int g = blockIdx.x * 256 + threadIdx.x;   // 0 .. NTOK*512-1
  int d = g & 511; int m = g >> 9;
  float zv = xz[(size_t)m * 1024 + 512 + d];
  gate[g] = (ys[g] + uc[g] * Dp[d]) * siluf_(zv);
}

// ---------- GEMM3: out[m,n] = gate[m,:] . W_out[n,:]  (M=4096,N=256,K=512) ----------
__global__ __launch_bounds__(256) void k_gemm3s(const float* __restrict__ gate,
    const float* __restrict__ Wout, float* __restrict__ out){
  __shared__ float sh[512];
  int m = blockIdx.x;
  sh[threadIdx.x]       = gate[(size_t)m * 512 + threadIdx.x];
  sh[threadIdx.x + 256] = gate[(size_t)m * 512 + 256 + threadIdx.x];
  __syncthreads();
  int n = threadIdx.x;
  float acc = 0.f;
  for (int k = 0; k < 512; k++)
    acc += sh[k] * Wout[(size_t)n * 512 + k];
  out[(size_t)m * 256 + n] = acc;
}

extern "C" void kernel_launch(void* const* d_in, const int* in_sizes, int n_in,
                              void* d_out, int out_size, void* d_ws, size_t ws_size,
                              hipStream_t stream) {
  const float* x      = (const float*)d_in[0];
  const float* C_SA   = (const float*)d_in[1];
  const float* gamma  = (const float*)d_in[2];
  const float* beta   = (const float*)d_in[3];
  const float* W_in   = (const float*)d_in[4];
  const float* conv_w = (const float*)d_in[5];
  const float* conv_b = (const float*)d_in[6];
  const float* W_x    = (const float*)d_in[7];
  const float* W_dt   = (const float*)d_in[8];
  const float* b_dt   = (const float*)d_in[9];
  const float* A_log  = (const float*)d_in[10];
  const float* Dw     = (const float*)d_in[11];
  const float* W_out  = (const float*)d_in[12];
  float* out = (float*)d_out;

  float* ws    = (float*)d_ws;
  float* xn    = ws;                        // 4096*256
  float* xz    = xn   + 4096*256;           // 4096*1024
  float* uc    = xz   + 4096*1024;          // 4096*512
  float* dbl   = uc   + 4096*512;           // 4096*80
  float* dtb   = dbl  + 4096*80;            // 4096*512
  float* ysb   = dtb  + 4096*512;           // 4096*512
  float* gate  = ysb  + 4096*512;           // 4096*512

  k_ln    <<<NTOK/4, 256, 0, stream>>>(x, gamma, beta, xn);
  k_gemm1s<<<dim3(4, NTOK), 256, 0, stream>>>(xn, W_in, xz);
  k_conv  <<<(NTOK*512)/256, 256, 0, stream>>>(xz, conv_w, conv_b, uc);
  k_gemm2s<<<NTOK, 128, 0, stream>>>(uc, W_x, dbl);
  k_dt    <<<(NTOK*512)/256, 256, 0, stream>>>(dbl, W_dt, b_dt, dtb);
  k_scan  <<<512, 256, 0, stream>>>(dtb, uc, dbl, C_SA, A_log, ysb);
  k_gate  <<<(NTOK*512)/256, 256, 0, stream>>>(ysb, uc, xz, Dw, gate);
  k_gemm3s<<<NTOK, 256, 0, stream>>>(gate, W_out, out);
}

// Round 5
// 397.839 us; speedup vs baseline: 3.4625x; 3.4625x over previous
//
#include <hip/hip_runtime.h>
#include <cstdint>
#include <cstddef>

#define B_    4
#define L_    1024
#define DIM_  256
#define DI_   512
#define NTOK  (B_*L_)

__device__ __forceinline__ float siluf_(float x){ return x / (1.0f + __expf(-x)); }
__device__ __forceinline__ float softplusf_(float x){
  return (x > 15.0f) ? x : log1pf(__expf(x));
}

// ---------- LayerNorm, materialized: one wave per token ----------
__global__ __launch_bounds__(256) void k_ln(const float* __restrict__ x,
    const float* __restrict__ gamma, const float* __restrict__ beta,
    float* __restrict__ xn){
  int tok  = blockIdx.x * 4 + (threadIdx.x >> 6);
  int lane = threadIdx.x & 63;
  float v[4];
  float s = 0.f, sq = 0.f;
  #pragma unroll
  for (int q = 0; q < 4; q++){
    v[q] = x[(size_t)tok * DIM_ + lane * 4 + q];
    s += v[q]; sq += v[q] * v[q];
  }
  #pragma unroll
  for (int off = 32; off; off >>= 1){
    s  += __shfl_xor(s,  off, 64);
    sq += __shfl_xor(sq, off, 64);
  }
  float mu = s * (1.0f / DIM_);
  float rs = rsqrtf(sq * (1.0f / DIM_) - mu * mu + 1e-5f);
  #pragma unroll
  for (int q = 0; q < 4; q++){
    int c = lane * 4 + q;
    xn[(size_t)tok * DIM_ + c] = (v[q] - mu) * rs * gamma[c] + beta[c];
  }
}

// ---------- GEMM1 tiled: xz[m,n] = xn[m,:] . W_in[n,:]  (M=4096,N=1024,K=256) ----------
__global__ __launch_bounds__(256) void k_gemm1(const float* __restrict__ xn,
    const float* __restrict__ Win, float* __restrict__ xz){
  __shared__ float As[16][64];
  __shared__ float Bs[16][64];
  int tid = threadIdx.x;
  int mBase = blockIdx.y * 64;
  int nBase = blockIdx.x * 64;
  int tx = tid & 15, ty = tid >> 4;
  int am = tid >> 2, ak = (tid & 3) << 2;
  float acc[4][4] = {};
  for (int kt = 0; kt < 256; kt += 16){
    float4 av = *(const float4*)(xn  + (size_t)(mBase+am)*256 + kt + ak);
    float4 bv = *(const float4*)(Win + (size_t)(nBase+am)*256 + kt + ak);
    As[ak+0][am]=av.x; As[ak+1][am]=av.y; As[ak+2][am]=av.z; As[ak+3][am]=av.w;
    Bs[ak+0][am]=bv.x; Bs[ak+1][am]=bv.y; Bs[ak+2][am]=bv.z; Bs[ak+3][am]=bv.w;
    __syncthreads();
    #pragma unroll
    for (int kk = 0; kk < 16; kk++){
      float a[4], b[4];
      #pragma unroll
      for (int i=0;i<4;i++) a[i] = As[kk][ty*4+i];
      #pragma unroll
      for (int j=0;j<4;j++) b[j] = Bs[kk][tx*4+j];
      #pragma unroll
      for (int i=0;i<4;i++)
        #pragma unroll
        for (int j=0;j<4;j++)
          acc[i][j] += a[i]*b[j];
    }
    __syncthreads();
  }
  #pragma unroll
  for (int i=0;i<4;i++){
    float4 o = make_float4(acc[i][0],acc[i][1],acc[i][2],acc[i][3]);
    *(float4*)(xz + (size_t)(mBase+ty*4+i)*1024 + nBase + tx*4) = o;
  }
}

// ---------- causal depthwise conv (w=4) + SiLU ----------
__global__ __launch_bounds__(256) void k_conv(const float* __restrict__ xz,
    const float* __restrict__ cw, const float* __restrict__ cb,
    float* __restrict__ uc){
  int g = blockIdx.x * 256 + threadIdx.x;      // 0 .. NTOK*512-1
  int d = g & 511;
  int tok = g >> 9;
  int t = tok & (L_ - 1);
  float w0 = cw[d*4+0], w1 = cw[d*4+1], w2 = cw[d*4+2], w3 = cw[d*4+3];
  const float* up = xz + (size_t)tok * 1024 + d;  // u = xz[:, :512]
  float acc = cb[d] + w3 * up[0];
  if (t >= 1) acc += w2 * up[-1 * 1024];
  if (t >= 2) acc += w1 * up[-2 * 1024];
  if (t >= 3) acc += w0 * up[-3 * 1024];
  uc[g] = siluf_(acc);
}

// ---------- GEMM2 tiled: dbl[m,n] = uc[m,:] . W_x[n,:]  (M=4096,N=80,K=512) ----------
__global__ __launch_bounds__(256) void k_gemm2(const float* __restrict__ uc,
    const float* __restrict__ Wx, float* __restrict__ dbl){
  __shared__ float As[16][64];
  __shared__ float Bs[16][80];
  int tid = threadIdx.x;
  int mBase = blockIdx.x * 64;
  int tx = tid & 15, ty = tid >> 4;
  int am = tid >> 2, ak = (tid & 3) << 2;
  float acc[4][5] = {};
  for (int kt = 0; kt < 512; kt += 16){
    float4 av = *(const float4*)(uc + (size_t)(mBase+am)*512 + kt + ak);
    As[ak+0][am]=av.x; As[ak+1][am]=av.y; As[ak+2][am]=av.z; As[ak+3][am]=av.w;
    for (int idx = tid; idx < 80*16; idx += 256){
      int bn = idx >> 4, bk = idx & 15;
      Bs[bk][bn] = Wx[(size_t)bn*512 + kt + bk];
    }
    __syncthreads();
    #pragma unroll
    for (int kk=0;kk<16;kk++){
      float a[4], b[5];
      #pragma unroll
      for (int i=0;i<4;i++) a[i] = As[kk][ty*4+i];
      #pragma unroll
      for (int j=0;j<5;j++) b[j] = Bs[kk][tx*5+j];
      #pragma unroll
      for (int i=0;i<4;i++)
        #pragma unroll
        for (int j=0;j<5;j++)
          acc[i][j] += a[i]*b[j];
    }
    __syncthreads();
  }
  #pragma unroll
  for (int i=0;i<4;i++)
    #pragma unroll
    for (int j=0;j<5;j++)
      dbl[(size_t)(mBase+ty*4+i)*80 + tx*5 + j] = acc[i][j];
}

// ---------- dt[m,d] = softplus(dbl[m,:16] . W_dt[d,:] + b_dt[d]) ----------
__global__ __launch_bounds__(256) void k_dt(const float* __restrict__ dbl,
    const float* __restrict__ Wdt, const float* __restrict__ bdt,
    float* __restrict__ dt){
  int g = blockIdx.x * 256 + threadIdx.x;
  int d = g & 511; int m = g >> 9;
  float acc = bdt[d];
  const float* r = dbl + (size_t)m * 80;
  #pragma unroll
  for (int k = 0; k < 16; k++)
    acc += r[k] * Wdt[d * 16 + k];
  dt[g] = softplusf_(acc);
}

// ---------- selective scan: one wave per (b,d); lane = state; T=8 batched reduction ----------
__global__ __launch_bounds__(256) void k_scan(const float* __restrict__ dt,
    const float* __restrict__ uc, const float* __restrict__ dbl,
    const float* __restrict__ C_SA, const float* __restrict__ A_log,
    float* __restrict__ ys){
  int wid  = (blockIdx.x * 256 + threadIdx.x) >> 6;  // 0..2047
  int lane = threadIdx.x & 63;
  int b = wid >> 9;
  int d = wid & 511;
  float A = -__expf(A_log[(size_t)d * 64 + lane]);
  float h = 0.0f;
  const float* dtp = dt   + (size_t)b * L_ * 512 + d;
  const float* ucp = uc   + (size_t)b * L_ * 512 + d;
  const float* Bp  = dbl  + (size_t)b * L_ * 80  + 16 + lane;
  const float* Cp  = C_SA + (size_t)b * L_ * 64  + lane;
  float*       yp_ = ys   + (size_t)b * L_ * 512 + d;
  for (int t0 = 0; t0 < L_; t0 += 8){
    // hoistable loads: none depend on h
    float dtv[8], uv[8], Bv[8], Cv[8];
    #pragma unroll
    for (int j = 0; j < 8; j++){
      dtv[j] = dtp[(size_t)(t0+j) * 512];
      uv[j]  = ucp[(size_t)(t0+j) * 512];
      Bv[j]  = Bp [(size_t)(t0+j) * 80];
      Cv[j]  = Cp [(size_t)(t0+j) * 64];
    }
    float yp[8];
    #pragma unroll
    for (int j = 0; j < 8; j++){
      float dA = __expf(dtv[j] * A);
      h = dA * h + (dtv[j] * uv[j]) * Bv[j];
      yp[j] = h * Cv[j];
    }
    // batched butterfly: 6 steps, 8 independent chains each
    #pragma unroll
    for (int off = 32; off; off >>= 1){
      #pragma unroll
      for (int j = 0; j < 8; j++)
        yp[j] += __shfl_xor(yp[j], off, 64);
    }
    if (lane == 0){
      #pragma unroll
      for (int j = 0; j < 8; j++)
        yp_[(size_t)(t0+j) * 512] = yp[j];
    }
  }
}

// ---------- gate: g[m,k] = (ys + uc*D[k]) * silu(z[m,k]) ----------
__global__ __launch_bounds__(256) void k_gate(const float* __restrict__ ys,
    const float* __restrict__ uc, const float* __restrict__ xz,
    const float* __restrict__ Dp, float* __restrict__ gate){
  int g = blockIdx.x * 256 + threadIdx.x;   // 0 .. NTOK*512-1
  int d = g & 511; int m = g >> 9;
  float zv = xz[(size_t)m * 1024 + 512 + d];
  gate[g] = (ys[g] + uc[g] * Dp[d]) * siluf_(zv);
}

// ---------- GEMM3 tiled: out[m,n] = gate[m,:] . W_out[n,:]  (M=4096,N=256,K=512) ----------
__global__ __launch_bounds__(256) void k_gemm3(const float* __restrict__ gate,
    const float* __restrict__ Wout, float* __restrict__ out){
  __shared__ float As[16][64];
  __shared__ float Bs[16][64];
  int tid = threadIdx.x;
  int mBase = blockIdx.y * 64;
  int nBase = blockIdx.x * 64;
  int tx = tid & 15, ty = tid >> 4;
  int am = tid >> 2, ak = (tid & 3) << 2;
  float acc[4][4] = {};
  for (int kt = 0; kt < 512; kt += 16){
    float4 av = *(const float4*)(gate + (size_t)(mBase+am)*512 + kt + ak);
    float4 bv = *(const float4*)(Wout + (size_t)(nBase+am)*512 + kt + ak);
    As[ak+0][am]=av.x; As[ak+1][am]=av.y; As[ak+2][am]=av.z; As[ak+3][am]=av.w;
    Bs[ak+0][am]=bv.x; Bs[ak+1][am]=bv.y; Bs[ak+2][am]=bv.z; Bs[ak+3][am]=bv.w;
    __syncthreads();
    #pragma unroll
    for (int kk=0;kk<16;kk++){
      float a[4], b[4];
      #pragma unroll
      for (int i=0;i<4;i++) a[i] = As[kk][ty*4+i];
      #pragma unroll
      for (int j=0;j<4;j++) b[j] = Bs[kk][tx*4+j];
      #pragma unroll
      for (int i=0;i<4;i++)
        #pragma unroll
        for (int j=0;j<4;j++)
          acc[i][j] += a[i]*b[j];
    }
    __syncthreads();
  }
  #pragma unroll
  for (int i=0;i<4;i++){
    float4 o = make_float4(acc[i][0],acc[i][1],acc[i][2],acc[i][3]);
    *(float4*)(out + (size_t)(mBase+ty*4+i)*256 + nBase + tx*4) = o;
  }
}

extern "C" void kernel_launch(void* const* d_in, const int* in_sizes, int n_in,
                              void* d_out, int out_size, void* d_ws, size_t ws_size,
                              hipStream_t stream) {
  const float* x      = (const float*)d_in[0];
  const float* C_SA   = (const float*)d_in[1];
  const float* gamma  = (const float*)d_in[2];
  const float* beta   = (const float*)d_in[3];
  const float* W_in   = (const float*)d_in[4];
  const float* conv_w = (const float*)d_in[5];
  const float* conv_b = (const float*)d_in[6];
  const float* W_x    = (const float*)d_in[7];
  const float* W_dt   = (const float*)d_in[8];
  const float* b_dt   = (const float*)d_in[9];
  const float* A_log  = (const float*)d_in[10];
  const float* Dw     = (const float*)d_in[11];
  const float* W_out  = (const float*)d_in[12];
  float* out = (float*)d_out;

  float* ws    = (float*)d_ws;
  float* xn    = ws;                        // 4096*256
  float* xz    = xn   + 4096*256;           // 4096*1024
  float* uc    = xz   + 4096*1024;          // 4096*512
  float* dbl   = uc   + 4096*512;           // 4096*80
  float* dtb   = dbl  + 4096*80;            // 4096*512
  float* ysb   = dtb  + 4096*512;           // 4096*512
  float* gate  = ysb  + 4096*512;           // 4096*512

  k_ln   <<<NTOK/4, 256, 0, stream>>>(x, gamma, beta, xn);
  k_gemm1<<<dim3(16, 64), 256, 0, stream>>>(xn, W_in, xz);
  k_conv <<<(NTOK*512)/256, 256, 0, stream>>>(xz, conv_w, conv_b, uc);
  k_gemm2<<<64, 256, 0, stream>>>(uc, W_x, dbl);
  k_dt   <<<(NTOK*512)/256, 256, 0, stream>>>(dbl, W_dt, b_dt, dtb);
  k_scan <<<512, 256, 0, stream>>>(dtb, uc, dbl, C_SA, A_log, ysb);
  k_gate <<<(NTOK*512)/256, 256, 0, stream>>>(ysb, uc, xz, Dw, gate);
  k_gemm3<<<dim3(4, 64), 256, 0, stream>>>(gate, W_out, out);
}